// Round 20
// baseline (557.183 us; speedup 1.0000x reference)
//
#include <hip/hip_runtime.h>

typedef __attribute__((ext_vector_type(8))) short short8;
typedef __attribute__((ext_vector_type(8))) unsigned short ushort8;
typedef __attribute__((ext_vector_type(4))) unsigned short ushort4v;
typedef __attribute__((ext_vector_type(4))) float f32x4;
typedef unsigned int uint;
typedef unsigned short ushort;

#define BB 8
#define CC 64
#define NPT 32768
#define RR 32
#define R3 32768
#define RP 34
#define RP2 1156
#define RP3 39304
#define BN_EPS 1e-4f

__device__ __forceinline__ ushort f2bf(float x) {
    uint u = __float_as_uint(x);
    u = (u + 0x7FFFu + ((u >> 16) & 1u)) >> 16;
    return (ushort)u;
}
__device__ __forceinline__ float bf2f(ushort u) {
    return __uint_as_float(((uint)u) << 16);
}
__device__ __forceinline__ void gload_lds16(const void* g, void* l) {
    __builtin_amdgcn_global_load_lds(
        (const __attribute__((address_space(1))) unsigned int*)g,
        (__attribute__((address_space(3))) unsigned int*)l, 16, 0, 0);
}

// ------- fused coord prep: mean -> maxmag -> norm + linked list (1 blk/batch) -
__global__ __launch_bounds__(1024) void k_prep(const float* __restrict__ coords,
                                               float* __restrict__ norm,
                                               int* __restrict__ nxt, int* __restrict__ head) {
    __shared__ float sb[1024];
    __shared__ float sm[4];
    int b = blockIdx.x;
    int tid = threadIdx.x;
    const float* cb = coords + (size_t)b * 3 * NPT;
    #pragma unroll
    for (int d = 0; d < 3; d++) {
        float s = 0.f;
        for (int i = tid; i < NPT; i += 1024) s += cb[(size_t)d*NPT + i];
        sb[tid] = s; __syncthreads();
        for (int off = 512; off > 0; off >>= 1) {
            if (tid < off) sb[tid] += sb[tid + off];
            __syncthreads();
        }
        if (tid == 0) sm[d] = sb[0] / (float)NPT;
        __syncthreads();
    }
    float m0 = sm[0], m1 = sm[1], m2 = sm[2];
    float mx = 0.f;
    for (int i = tid; i < NPT; i += 1024) {
        float x = cb[i] - m0, y = cb[NPT + i] - m1, z = cb[2*NPT + i] - m2;
        mx = fmaxf(mx, x*x + y*y + z*z);
    }
    sb[tid] = mx; __syncthreads();
    for (int off = 512; off > 0; off >>= 1) {
        if (tid < off) sb[tid] = fmaxf(sb[tid], sb[tid + off]);
        __syncthreads();
    }
    if (tid == 0) sm[3] = sqrtf(sb[0]) * 2.0f;
    __syncthreads();
    float denom = sm[3];
    for (int n = tid; n < NPT; n += 1024) {
        float v0 = (cb[n] - m0) / denom + 0.5f;
        float v1 = (cb[NPT + n] - m1) / denom + 0.5f;
        float v2 = (cb[2*NPT + n] - m2) / denom + 0.5f;
        v0 = fminf(fmaxf(v0 * (float)RR, 0.f), (float)(RR - 1));
        v1 = fminf(fmaxf(v1 * (float)RR, 0.f), (float)(RR - 1));
        v2 = fminf(fmaxf(v2 * (float)RR, 0.f), (float)(RR - 1));
        norm[((size_t)b*3 + 0)*NPT + n] = v0;
        norm[((size_t)b*3 + 1)*NPT + n] = v1;
        norm[((size_t)b*3 + 2)*NPT + n] = v2;
        int pf = (((int)rintf(v0)+1)*RP + ((int)rintf(v1)+1))*RP + ((int)rintf(v2)+1);
        nxt[b*NPT + n] = atomicExch(&head[b*RP3 + pf], n);
    }
}

// ---------------- feat transpose: [b][64][N] f32 -> [b][N][64] bf16 ----------
__global__ __launch_bounds__(256) void k_transpose(const float* __restrict__ feat,
                                                   ushort* __restrict__ featT) {
    __shared__ float t[64][65];
    int b = blockIdx.y;
    int n0 = blockIdx.x * 64;
    for (int i = threadIdx.x; i < 4096; i += 256) {
        int ci = i >> 6, nl = i & 63;
        t[ci][nl] = feat[((size_t)(b*CC + ci))*NPT + n0 + nl];
    }
    __syncthreads();
    for (int i = threadIdx.x; i < 4096; i += 256) {
        int nl = i >> 6, ci = i & 63;
        featT[((size_t)b*NPT + n0 + nl)*64 + ci] = f2bf(t[ci][nl]);
    }
}

// ---------------- gather-mean voxelize: list walk -> bf16 gbf directly -------
__global__ __launch_bounds__(256) void k_gather(const ushort* __restrict__ featT,
                                                const int* __restrict__ head,
                                                const int* __restrict__ nxt,
                                                ushort* __restrict__ gbf) {
    int b = blockIdx.y;
    int v = blockIdx.x * 4 + (threadIdx.x >> 6);   // grid.x = 9826 -> 39304 exactly
    int lane = threadIdx.x & 63;
    float a = 0.f;
    int c = 0;
    int p = head[b*RP3 + v];
    while (p >= 0) {
        a += bf2f(featT[((size_t)b*NPT + p)*64 + lane]);
        c++;
        p = nxt[b*NPT + p];
    }
    float r = (c > 0) ? a / (float)c : 0.f;
    gbf[((size_t)((b*2 + (lane >> 5))*RP3) + v)*32 + (lane & 31)] = f2bf(r);
}

// ---------------- weight transform, both layers in one launch ----------------
__global__ void k_wt2(const float* __restrict__ w1, const float* __restrict__ w2,
                      ushort* __restrict__ wT1, ushort* __restrict__ wT2) {
    int s = blockIdx.x * 256 + threadIdx.x;     // grid 864*256 = 221184 exactly
    const float* w = (s < 110592) ? w1 : w2;
    ushort* wT = (s < 110592) ? wT1 : wT2;
    int si = (s < 110592) ? s : s - 110592;
    int ci = si & 31;
    int co = (si >> 5) & 63;
    int t  = (si >> 11) % 27;
    int ch = si / 55296;
    wT[si] = f2bf(w[(size_t)co*1728 + (size_t)(ch*32 + ci)*27 + t]);
}

// -------- fused finalize + BN+leaky+pack: CL raw bf16 -> padded CL bf16 -------
__global__ void k_bnpack(const ushort* __restrict__ raw,
                         const float* __restrict__ gs, const float* __restrict__ gq,
                         const float* __restrict__ gamma, const float* __restrict__ beta,
                         ushort* __restrict__ gbf) {
    __shared__ float s_sc[64], s_sh[64];
    if (threadIdx.x < 64) {
        int c = threadIdx.x;
        const float cntf = 262144.0f;
        float m = gs[c] / cntf;
        float vv = gq[c] / cntf - m*m;
        float scv = gamma[c] * rsqrtf(fmaxf(vv, 0.0f) + BN_EPS);
        s_sc[c] = scv;
        s_sh[c] = beta[c] - m*scv;
    }
    __syncthreads();
    int s = blockIdx.x * 256 + threadIdx.x;      // grid 9826*256 = 2515456 exactly
    int j = s & 3;
    int tmp = s >> 2;
    int v = tmp % RP3;
    int t2 = tmp / RP3;
    int ch = t2 & 1, b = t2 >> 1;
    int gz = v / RP2; int r = v - gz*RP2;
    int gy = r / RP;  int gx = r - gy*RP;
    ushort8 o;
    if (gz >= 1 && gz <= 32 && gy >= 1 && gy <= 32 && gx >= 1 && gx <= 32) {
        int uvox = ((gz-1)*RR + (gy-1))*RR + (gx-1);
        int cb = ch*32 + j*8;
        ushort8 rv = *(const ushort8*)(raw + ((size_t)b*R3 + uvox)*64 + cb);
        #pragma unroll
        for (int e = 0; e < 8; e++) {
            float x = bf2f(rv[e])*s_sc[cb + e] + s_sh[cb + e];
            x = x >= 0.f ? x : 0.1f*x;
            o[e] = f2bf(x);
        }
    } else {
        #pragma unroll
        for (int e = 0; e < 8; e++) o[e] = 0;
    }
    *(ushort8*)(gbf + ((size_t)((b*2 + ch)*RP3) + v)*32 + j*8) = o;
}

// ---------------- MFMA conv + inline BN stats (frozen) ----------------
__global__ __launch_bounds__(512) void k_conv_mfma(
    const ushort* __restrict__ gbf,   // [8][2][RP3][32] bf16
    const ushort* __restrict__ wT,    // [2][27][64][32] bf16
    ushort* __restrict__ rawbf,       // [8][R3][64] channel-LAST bf16
    float* __restrict__ gs, float* __restrict__ gq)
{
    __shared__ uint4 lds4[2 * 3888];  // 124416 B
    const int d0r = blockIdx.x;
    const int d0 = (d0r & 7) * 4 + (d0r >> 3);   // XCD-chunked bijection (32 = 8*4)
    const int quad = blockIdx.y, b = blockIdx.z;
    const int y0 = (quad >> 1) * 16, x0 = (quad & 1) * 16;
    const int tid = threadIdx.x;
    const int lane = tid & 63;
    const int wid = tid >> 6;
    const int mgroup = wid & 1, ngroup = wid >> 1;
    const int l15 = lane & 15, kgrp = lane >> 4;

    f32x4 acc[2][4];
    #pragma unroll
    for (int mf = 0; mf < 2; mf++)
        #pragma unroll
        for (int f = 0; f < 4; f++) acc[mf][f] = (f32x4)(0.0f);

    const int coA = mgroup*32 + l15;
    const int coB = coA + 16;

    // stage ch=0 into buffer A
    {
        const char* gbase = (const char*)gbf + (size_t)(b*2 + 0) * ((size_t)RP3 * 64);
        for (int c = tid; c < 3888; c += 512) {
            int row = c >> 2, j = c & 3;
            int z = row / 324; int rem = row - z*324;
            int y = rem / 18;  int xl = rem - y*18;
            int srcj = j ^ ((xl >> 1) & 3);
            const char* src = gbase +
                (size_t)((d0 + z)*RP2 + (y0 + y)*RP + (x0 + xl)) * 64 + srcj*16;
            gload_lds16(src, (char*)lds4 + c*16);
        }
    }
    __syncthreads();
    // issue stage ch=1 into buffer B (flies under ch0 compute)
    {
        const char* gbase = (const char*)gbf + (size_t)(b*2 + 1) * ((size_t)RP3 * 64);
        for (int c = tid; c < 3888; c += 512) {
            int row = c >> 2, j = c & 3;
            int z = row / 324; int rem = row - z*324;
            int y = rem / 18;  int xl = rem - y*18;
            int srcj = j ^ ((xl >> 1) & 3);
            const char* src = gbase +
                (size_t)((d0 + z)*RP2 + (y0 + y)*RP + (x0 + xl)) * 64 + srcj*16;
            gload_lds16(src, (char*)lds4 + 62208 + c*16);
        }
    }

    #pragma unroll
    for (int ch = 0; ch < 2; ch++) {
        if (ch == 1) __syncthreads();
        const char* lbase = (const char*)lds4 + ch * 62208;
        const ushort* wbase = wT + (size_t)ch * 27 * 2048 + kgrp*8;
        short8 wq[3][2];
        #pragma unroll
        for (int pre = 0; pre < 3; pre++) {
            wq[pre][0] = *(const short8*)(wbase + (size_t)pre*2048 + coA*32);
            wq[pre][1] = *(const short8*)(wbase + (size_t)pre*2048 + coB*32);
        }
        __builtin_amdgcn_s_setprio(1);
        #pragma unroll
        for (int t = 0; t < 27; t++) {
            const int t0 = t / 9, t1 = (t / 3) % 3, t2 = t % 3;
            const int slot = t % 3;
            int x = l15 + t2;
            int inrow = (kgrp ^ ((x >> 1) & 3)) << 4;
            #pragma unroll
            for (int f = 0; f < 4; f++) {
                int y = ngroup*4 + f + t1;
                int vox = (t0*18 + y)*18 + x;
                short8 bfr = *(const short8*)(lbase + vox*64 + inrow);
                acc[0][f] = __builtin_amdgcn_mfma_f32_16x16x32_bf16(wq[slot][0], bfr, acc[0][f], 0, 0, 0);
                acc[1][f] = __builtin_amdgcn_mfma_f32_16x16x32_bf16(wq[slot][1], bfr, acc[1][f], 0, 0, 0);
            }
            if (t + 3 < 27) {
                wq[slot][0] = *(const short8*)(wbase + (size_t)(t+3)*2048 + coA*32);
                wq[slot][1] = *(const short8*)(wbase + (size_t)(t+3)*2048 + coB*32);
            }
        }
        __builtin_amdgcn_s_setprio(0);
    }
    int d2 = x0 + l15;
    #pragma unroll
    for (int f = 0; f < 4; f++) {
        int d1 = y0 + ngroup*4 + f;
        int vox = (d0*RR + d1)*RR + d2;
        ushort* dst = rawbf + ((size_t)b*R3 + vox)*64 + mgroup*32 + kgrp*4;
        ushort4v o0, o1;
        #pragma unroll
        for (int e = 0; e < 4; e++) { o0[e] = f2bf(acc[0][f][e]); o1[e] = f2bf(acc[1][f][e]); }
        *(ushort4v*)dst = o0;
        *(ushort4v*)(dst + 16) = o1;
    }
    // inline BN stats (exact, from f32 accumulators)
    __syncthreads();
    float* bins = (float*)lds4;
    if (tid < 128) bins[tid] = 0.f;
    __syncthreads();
    float sv[2][4], qv[2][4];
    #pragma unroll
    for (int mf = 0; mf < 2; mf++)
        #pragma unroll
        for (int e = 0; e < 4; e++) {
            float s = 0.f, q = 0.f;
            #pragma unroll
            for (int f = 0; f < 4; f++) {
                float v = acc[mf][f][e];
                s += v; q += v*v;
            }
            #pragma unroll
            for (int m = 1; m < 16; m <<= 1) {
                s += __shfl_xor(s, m);
                q += __shfl_xor(q, m);
            }
            sv[mf][e] = s; qv[mf][e] = q;
        }
    if (l15 == 0) {
        #pragma unroll
        for (int mf = 0; mf < 2; mf++)
            #pragma unroll
            for (int e = 0; e < 4; e++) {
                int co = mgroup*32 + mf*16 + kgrp*4 + e;
                atomicAdd(&bins[co], sv[mf][e]);
                atomicAdd(&bins[64 + co], qv[mf][e]);
            }
    }
    __syncthreads();
    if (tid < 64) { atomicAdd(&gs[tid], bins[tid]); atomicAdd(&gq[tid], bins[64 + tid]); }
}

// ------- point branch: stats + IN-PLACE featT -> P (channel-last) ------------
__global__ __launch_bounds__(256) void k_point_stats_P(ushort* __restrict__ featT,
                                                       const float* __restrict__ wp,
                                                       float* __restrict__ gs,
                                                       float* __restrict__ gq) {
    __shared__ float ls[64], lq[64];
    int b = blockIdx.y;
    int n = blockIdx.x * 256 + threadIdx.x;
    if (threadIdx.x < 64) { ls[threadIdx.x] = 0.f; lq[threadIdx.x] = 0.f; }
    __syncthreads();
    ushort* rowp = featT + ((size_t)b*NPT + n)*64;
    float fr[64];
    {
        const ushort8* fp = (const ushort8*)rowp;
        #pragma unroll
        for (int r = 0; r < 8; r++) {
            ushort8 u = fp[r];
            #pragma unroll
            for (int e = 0; e < 8; e++) fr[r*8 + e] = bf2f(u[e]);
        }
    }
    int lane = threadIdx.x & 63;
    float ps[64];
    #pragma unroll
    for (int co = 0; co < 64; co++) {
        float p = 0.f;
        #pragma unroll
        for (int r = 0; r < 16; r++) {
            f32x4 w4 = *(const f32x4*)(wp + co*64 + r*4);   // wave-uniform -> s_load
            p = fmaf(w4[0], fr[r*4+0], p); p = fmaf(w4[1], fr[r*4+1], p);
            p = fmaf(w4[2], fr[r*4+2], p); p = fmaf(w4[3], fr[r*4+3], p);
        }
        ps[co] = p;
        float s = p, q = p*p;
        #pragma unroll
        for (int m = 1; m < 64; m <<= 1) {
            s += __shfl_xor(s, m);
            q += __shfl_xor(q, m);
        }
        if (lane == 0) { atomicAdd(&ls[co], s); atomicAdd(&lq[co], q); }
    }
    // in-place overwrite: P row (channel-last), vectorized
    #pragma unroll
    for (int g = 0; g < 8; g++) {
        ushort8 o;
        #pragma unroll
        for (int e = 0; e < 8; e++) o[e] = f2bf(ps[g*8 + e]);
        *(ushort8*)(rowp + g*8) = o;
    }
    __syncthreads();
    if (threadIdx.x < 64) {
        atomicAdd(&gs[threadIdx.x], ls[threadIdx.x]);
        atomicAdd(&gq[threadIdx.x], lq[threadIdx.x]);
    }
}

// ------ final: fused finalize(BN2,BNp) + devox(bn2+leaky) + point + add ------
__global__ __launch_bounds__(256) void k_final4(
    const ushort* __restrict__ x2raw, // [B][R3][64] conv2 RAW bf16 channel-last
    const float* __restrict__ norm,
    const ushort* __restrict__ P,     // [B][N][64] bf16 point-branch raw (channel-last)
    const float* __restrict__ gs2, const float* __restrict__ gq2,
    const float* __restrict__ g2, const float* __restrict__ be2,
    const float* __restrict__ gsp, const float* __restrict__ gqp,
    const float* __restrict__ gp, const float* __restrict__ bep,
    float* __restrict__ out)          // [B][64][N]
{
    __shared__ float s_sc[64], s_sh[64], s_scp[64], s_shp[64];
    int b = blockIdx.y;
    int tid = threadIdx.x;
    const float cntf = 262144.0f;
    if (tid < 64) {
        int c = tid;
        float m = gs2[c] / cntf;
        float vv = gq2[c] / cntf - m*m;
        float scv = g2[c] * rsqrtf(fmaxf(vv, 0.0f) + BN_EPS);
        s_sc[c] = scv; s_sh[c] = be2[c] - m*scv;
    } else if (tid < 128) {
        int c = tid - 64;
        float m = gsp[c] / cntf;
        float vv = gqp[c] / cntf - m*m;
        float scv = gp[c] * rsqrtf(fmaxf(vv, 0.0f) + BN_EPS);
        s_scp[c] = scv; s_shp[c] = bep[c] - m*scv;
    }
    __syncthreads();
    int pt = blockIdx.x * 64 + (tid & 63);
    int q = tid >> 6;                 // channel quarter, uniform per wave
    float v0 = norm[((size_t)b*3 + 0)*NPT + pt];
    float v1 = norm[((size_t)b*3 + 1)*NPT + pt];
    float v2 = norm[((size_t)b*3 + 2)*NPT + pt];
    int l0 = (int)floorf(v0), l1 = (int)floorf(v1), l2 = (int)floorf(v2);
    float f0 = v0 - (float)l0, f1 = v1 - (float)l1, f2 = v2 - (float)l2;
    int h0 = min(l0 + 1, RR - 1), h1 = min(l1 + 1, RR - 1), h2 = min(l2 + 1, RR - 1);

    f32x4 scv[4], shv[4];
    #pragma unroll
    for (int r = 0; r < 4; r++) {
        scv[r] = *(const f32x4*)&s_sc[q*16 + r*4];
        shv[r] = *(const f32x4*)&s_sh[q*16 + r*4];
    }

    f32x4 a4[4];
    #pragma unroll
    for (int r = 0; r < 4; r++) a4[r] = (f32x4)(0.0f);
    #pragma unroll
    for (int c = 0; c < 8; c++) {
        int xi = (c & 4) ? h0 : l0; float wx = (c & 4) ? f0 : 1.f - f0;
        int yi = (c & 2) ? h1 : l1; float wy = (c & 2) ? f1 : 1.f - f1;
        int zi = (c & 1) ? h2 : l2; float wz = (c & 1) ? f2 : 1.f - f2;
        float w = wx * wy * wz;
        const ushort* g = x2raw +
            ((size_t)b*R3 + (size_t)((xi*RR + yi)*RR + zi))*64 + q*16;
        ushort8 rv0 = *(const ushort8*)g;
        ushort8 rv1 = *(const ushort8*)(g + 8);
        #pragma unroll
        for (int r = 0; r < 2; r++) {
            #pragma unroll
            for (int e = 0; e < 4; e++) {
                float x = bf2f(rv0[r*4 + e])*scv[r][e] + shv[r][e];
                x = x >= 0.f ? x : 0.1f*x;
                a4[r][e] = fmaf(w, x, a4[r][e]);
                float x2 = bf2f(rv1[r*4 + e])*scv[2 + r][e] + shv[2 + r][e];
                x2 = x2 >= 0.f ? x2 : 0.1f*x2;
                a4[2 + r][e] = fmaf(w, x2, a4[2 + r][e]);
            }
        }
    }
    const ushort* pr = P + ((size_t)b*NPT + pt)*64 + q*16;
    ushort8 pv0 = *(const ushort8*)pr;
    ushort8 pv1 = *(const ushort8*)(pr + 8);
    #pragma unroll
    for (int r = 0; r < 4; r++) {
        #pragma unroll
        for (int e = 0; e < 4; e++) {
            int idx = r*4 + e;
            int co = q*16 + idx;
            float p = bf2f(idx < 8 ? pv0[idx] : pv1[idx - 8]);
            p = p * s_scp[co] + s_shp[co];
            p = fmaxf(p, 0.f);
            out[((size_t)(b*64 + co))*NPT + pt] = a4[r][e] + p;
        }
    }
}

extern "C" void kernel_launch(void* const* d_in, const int* in_sizes, int n_in,
                              void* d_out, int out_size, void* d_ws, size_t ws_size,
                              hipStream_t stream) {
    const float* feat   = (const float*)d_in[0];
    const float* coords = (const float*)d_in[1];
    const float* w1  = (const float*)d_in[2];
    const float* g1  = (const float*)d_in[4];
    const float* be1 = (const float*)d_in[5];
    const float* w2  = (const float*)d_in[6];
    const float* g2  = (const float*)d_in[8];
    const float* be2 = (const float*)d_in[9];
    const float* wp  = (const float*)d_in[10];
    const float* gp  = (const float*)d_in[12];
    const float* bep = (const float*)d_in[13];
    float* out = (float*)d_out;
    float* ws  = (float*)d_ws;

    // workspace layout (float offsets):
    //   stats  384      -> [32, 416)            (s1,q1,s2,q2,sp,qp)
    //   norm   786432   -> [1024, 787456)
    //   nxt    262144   -> [787456, 1049600)    (int)
    //   head   314432   -> [1049600, 1364032)   (int, 8*RP3)
    //   rawbf  4194304  -> [1364032, 5558336)   bf16 [8][R3][64] conv raw out
    //   wT1    55296    -> [21487680, 21542976)
    //   wT2    55296    -> [21542976, 21598272)
    //   gbf    10061824 -> [21598272, 31660096)  bf16 padded grid
    //   featT  8388608  -> [31660096, 40048704)  bf16 [8][N][64]; becomes P in-place
    float* mean_unused = ws;  (void)mean_unused;
    float* stats  = ws + 32;
    float* norm   = ws + 1024;
    int*   nxt    = (int*)(ws + 787456);
    int*   head   = (int*)(ws + 1049600);
    ushort* rawbf = (ushort*)(ws + 1364032);
    ushort* wT1   = (ushort*)(ws + 21487680);
    ushort* wT2   = (ushort*)(ws + 21542976);
    ushort* gbf   = (ushort*)(ws + 21598272);
    ushort* featT = (ushort*)(ws + 31660096);   // overwritten in-place as P

    hipMemsetAsync(stats, 0, 384 * sizeof(float), stream);
    hipMemsetAsync(head, 0xFF, 314432ull * sizeof(int), stream);   // head = -1

    k_wt2<<<864, 256, 0, stream>>>(w1, w2, wT1, wT2);
    k_prep<<<8, 1024, 0, stream>>>(coords, norm, nxt, head);
    k_transpose<<<dim3(512, 8), 256, 0, stream>>>(feat, featT);
    k_gather<<<dim3(9826, 8), 256, 0, stream>>>(featT, head, nxt, gbf);

    // conv1 (+inline stats1): gbf -> rawbf (bf16)
    k_conv_mfma<<<dim3(32, 4, 8), 512, 0, stream>>>(gbf, wT1, rawbf, stats + 0, stats + 64);
    // fused finalize1 + BN1+leaky+pack: rawbf -> gbf
    k_bnpack<<<9826, 256, 0, stream>>>(rawbf, stats + 0, stats + 64, g1, be1, gbf);

    // conv2 (+inline stats2): gbf -> rawbf
    k_conv_mfma<<<dim3(32, 4, 8), 512, 0, stream>>>(gbf, wT2, rawbf, stats + 128, stats + 192);

    // point branch: stats + in-place featT -> P (channel-last)
    k_point_stats_P<<<dim3(128, 8), 256, 0, stream>>>(featT, wp, stats + 256, stats + 320);

    // final: fused finalize(2,p) + devox BN2+leaky + point add
    k_final4<<<dim3(512, 8), 256, 0, stream>>>(rawbf, norm, featT,
                                               stats + 128, stats + 192, g2, be2,
                                               stats + 256, stats + 320, gp, bep,
                                               out);
}

// Round 21
// 484.979 us; speedup vs baseline: 1.1489x; 1.1489x over previous
//
#include <hip/hip_runtime.h>

typedef __attribute__((ext_vector_type(8))) short short8;
typedef __attribute__((ext_vector_type(8))) unsigned short ushort8;
typedef __attribute__((ext_vector_type(4))) unsigned short ushort4v;
typedef __attribute__((ext_vector_type(4))) float f32x4;
typedef unsigned int uint;
typedef unsigned short ushort;

#define BB 8
#define CC 64
#define NPT 32768
#define RR 32
#define R3 32768
#define RP 34
#define RP2 1156
#define RP3 39304
#define BN_EPS 1e-4f

__device__ __forceinline__ ushort f2bf(float x) {
    uint u = __float_as_uint(x);
    u = (u + 0x7FFFu + ((u >> 16) & 1u)) >> 16;
    return (ushort)u;
}
__device__ __forceinline__ float bf2f(ushort u) {
    return __uint_as_float(((uint)u) << 16);
}
__device__ __forceinline__ void gload_lds16(const void* g, void* l) {
    __builtin_amdgcn_global_load_lds(
        (const __attribute__((address_space(1))) unsigned int*)g,
        (__attribute__((address_space(3))) unsigned int*)l, 16, 0, 0);
}

// ---------------- coord normalization (round-19 proven) ----------------
__global__ void k_mean(const float* __restrict__ coords, float* __restrict__ mean) {
    __shared__ float sbuf[256];
    int bd = blockIdx.x;
    const float* c = coords + (size_t)bd * NPT;
    float s = 0.f;
    for (int i = threadIdx.x; i < NPT; i += 256) s += c[i];
    sbuf[threadIdx.x] = s; __syncthreads();
    for (int off = 128; off > 0; off >>= 1) {
        if (threadIdx.x < off) sbuf[threadIdx.x] += sbuf[threadIdx.x + off];
        __syncthreads();
    }
    if (threadIdx.x == 0) mean[bd] = sbuf[0] / (float)NPT;
}

__global__ void k_maxmag(const float* __restrict__ coords, const float* __restrict__ mean,
                         float* __restrict__ maxmag) {
    __shared__ float sbuf[256];
    int b = blockIdx.x;
    float m0 = mean[b*3], m1 = mean[b*3+1], m2 = mean[b*3+2];
    const float* c = coords + (size_t)b * 3 * NPT;
    float mx = 0.f;
    for (int i = threadIdx.x; i < NPT; i += 256) {
        float x = c[i] - m0, y = c[NPT + i] - m1, z = c[2*NPT + i] - m2;
        mx = fmaxf(mx, x*x + y*y + z*z);
    }
    sbuf[threadIdx.x] = mx; __syncthreads();
    for (int off = 128; off > 0; off >>= 1) {
        if (threadIdx.x < off) sbuf[threadIdx.x] = fmaxf(sbuf[threadIdx.x], sbuf[threadIdx.x + off]);
        __syncthreads();
    }
    if (threadIdx.x == 0) maxmag[b] = sqrtf(sbuf[0]);
}

// norm coords + build per-voxel linked list (head/nxt), padded voxel index
__global__ void k_norm(const float* __restrict__ coords, const float* __restrict__ mean,
                       const float* __restrict__ maxmag,
                       float* __restrict__ norm, int* __restrict__ nxt, int* __restrict__ head) {
    int b = blockIdx.y;
    int n = blockIdx.x * 256 + threadIdx.x;
    float denom = maxmag[b] * 2.0f;
    int vi[3];
    #pragma unroll
    for (int d = 0; d < 3; d++) {
        float v = (coords[((size_t)b*3 + d)*NPT + n] - mean[b*3 + d]) / denom + 0.5f;
        v *= (float)RR;
        v = fminf(fmaxf(v, 0.0f), (float)(RR - 1));
        norm[((size_t)b*3 + d)*NPT + n] = v;
        vi[d] = (int)rintf(v);
    }
    int pf = ((vi[0]+1)*RP + (vi[1]+1))*RP + (vi[2]+1);
    nxt[b*NPT + n] = atomicExch(&head[b*RP3 + pf], n);
}

// ---------------- feat transpose: [b][64][N] f32 -> [b][N][64] bf16 ----------
__global__ __launch_bounds__(256) void k_transpose(const float* __restrict__ feat,
                                                   ushort* __restrict__ featT) {
    __shared__ float t[64][65];
    int b = blockIdx.y;
    int n0 = blockIdx.x * 64;
    for (int i = threadIdx.x; i < 4096; i += 256) {
        int ci = i >> 6, nl = i & 63;
        t[ci][nl] = feat[((size_t)(b*CC + ci))*NPT + n0 + nl];
    }
    __syncthreads();
    for (int i = threadIdx.x; i < 4096; i += 256) {
        int nl = i >> 6, ci = i & 63;
        featT[((size_t)b*NPT + n0 + nl)*64 + ci] = f2bf(t[ci][nl]);
    }
}

// ---------------- gather-mean voxelize: list walk -> bf16 gbf directly -------
__global__ __launch_bounds__(256) void k_gather(const ushort* __restrict__ featT,
                                                const int* __restrict__ head,
                                                const int* __restrict__ nxt,
                                                ushort* __restrict__ gbf) {
    int b = blockIdx.y;
    int v = blockIdx.x * 4 + (threadIdx.x >> 6);   // grid.x = 9826 -> 39304 exactly
    int lane = threadIdx.x & 63;
    float a = 0.f;
    int c = 0;
    int p = head[b*RP3 + v];
    while (p >= 0) {
        a += bf2f(featT[((size_t)b*NPT + p)*64 + lane]);
        c++;
        p = nxt[b*NPT + p];
    }
    float r = (c > 0) ? a / (float)c : 0.f;
    gbf[((size_t)((b*2 + (lane >> 5))*RP3) + v)*32 + (lane & 31)] = f2bf(r);
}

// ---------------- weight transform, both layers in one launch ----------------
__global__ void k_wt2(const float* __restrict__ w1, const float* __restrict__ w2,
                      ushort* __restrict__ wT1, ushort* __restrict__ wT2) {
    int s = blockIdx.x * 256 + threadIdx.x;     // grid 864*256 = 221184 exactly
    const float* w = (s < 110592) ? w1 : w2;
    ushort* wT = (s < 110592) ? wT1 : wT2;
    int si = (s < 110592) ? s : s - 110592;
    int ci = si & 31;
    int co = (si >> 5) & 63;
    int t  = (si >> 11) % 27;
    int ch = si / 55296;
    wT[si] = f2bf(w[(size_t)co*1728 + (size_t)(ch*32 + ci)*27 + t]);
}

// -------- fused finalize + BN+leaky+pack: CL raw bf16 -> padded CL bf16 -------
__global__ void k_bnpack(const ushort* __restrict__ raw,
                         const float* __restrict__ gs, const float* __restrict__ gq,
                         const float* __restrict__ gamma, const float* __restrict__ beta,
                         ushort* __restrict__ gbf) {
    __shared__ float s_sc[64], s_sh[64];
    if (threadIdx.x < 64) {
        int c = threadIdx.x;
        const float cntf = 262144.0f;
        float m = gs[c] / cntf;
        float vv = gq[c] / cntf - m*m;
        float scv = gamma[c] * rsqrtf(fmaxf(vv, 0.0f) + BN_EPS);
        s_sc[c] = scv;
        s_sh[c] = beta[c] - m*scv;
    }
    __syncthreads();
    int s = blockIdx.x * 256 + threadIdx.x;      // grid 9826*256 = 2515456 exactly
    int j = s & 3;
    int tmp = s >> 2;
    int v = tmp % RP3;
    int t2 = tmp / RP3;
    int ch = t2 & 1, b = t2 >> 1;
    int gz = v / RP2; int r = v - gz*RP2;
    int gy = r / RP;  int gx = r - gy*RP;
    ushort8 o;
    if (gz >= 1 && gz <= 32 && gy >= 1 && gy <= 32 && gx >= 1 && gx <= 32) {
        int uvox = ((gz-1)*RR + (gy-1))*RR + (gx-1);
        int cb = ch*32 + j*8;
        ushort8 rv = *(const ushort8*)(raw + ((size_t)b*R3 + uvox)*64 + cb);
        #pragma unroll
        for (int e = 0; e < 8; e++) {
            float x = bf2f(rv[e])*s_sc[cb + e] + s_sh[cb + e];
            x = x >= 0.f ? x : 0.1f*x;
            o[e] = f2bf(x);
        }
    } else {
        #pragma unroll
        for (int e = 0; e < 8; e++) o[e] = 0;
    }
    *(ushort8*)(gbf + ((size_t)((b*2 + ch)*RP3) + v)*32 + j*8) = o;
}

// ---------------- MFMA conv + inline BN stats (frozen) ----------------
__global__ __launch_bounds__(512) void k_conv_mfma(
    const ushort* __restrict__ gbf,   // [8][2][RP3][32] bf16
    const ushort* __restrict__ wT,    // [2][27][64][32] bf16
    ushort* __restrict__ rawbf,       // [8][R3][64] channel-LAST bf16
    float* __restrict__ gs, float* __restrict__ gq)
{
    __shared__ uint4 lds4[2 * 3888];  // 124416 B
    const int d0r = blockIdx.x;
    const int d0 = (d0r & 7) * 4 + (d0r >> 3);   // XCD-chunked bijection (32 = 8*4)
    const int quad = blockIdx.y, b = blockIdx.z;
    const int y0 = (quad >> 1) * 16, x0 = (quad & 1) * 16;
    const int tid = threadIdx.x;
    const int lane = tid & 63;
    const int wid = tid >> 6;
    const int mgroup = wid & 1, ngroup = wid >> 1;
    const int l15 = lane & 15, kgrp = lane >> 4;

    f32x4 acc[2][4];
    #pragma unroll
    for (int mf = 0; mf < 2; mf++)
        #pragma unroll
        for (int f = 0; f < 4; f++) acc[mf][f] = (f32x4)(0.0f);

    const int coA = mgroup*32 + l15;
    const int coB = coA + 16;

    // stage ch=0 into buffer A
    {
        const char* gbase = (const char*)gbf + (size_t)(b*2 + 0) * ((size_t)RP3 * 64);
        for (int c = tid; c < 3888; c += 512) {
            int row = c >> 2, j = c & 3;
            int z = row / 324; int rem = row - z*324;
            int y = rem / 18;  int xl = rem - y*18;
            int srcj = j ^ ((xl >> 1) & 3);
            const char* src = gbase +
                (size_t)((d0 + z)*RP2 + (y0 + y)*RP + (x0 + xl)) * 64 + srcj*16;
            gload_lds16(src, (char*)lds4 + c*16);
        }
    }
    __syncthreads();
    // issue stage ch=1 into buffer B (flies under ch0 compute)
    {
        const char* gbase = (const char*)gbf + (size_t)(b*2 + 1) * ((size_t)RP3 * 64);
        for (int c = tid; c < 3888; c += 512) {
            int row = c >> 2, j = c & 3;
            int z = row / 324; int rem = row - z*324;
            int y = rem / 18;  int xl = rem - y*18;
            int srcj = j ^ ((xl >> 1) & 3);
            const char* src = gbase +
                (size_t)((d0 + z)*RP2 + (y0 + y)*RP + (x0 + xl)) * 64 + srcj*16;
            gload_lds16(src, (char*)lds4 + 62208 + c*16);
        }
    }

    #pragma unroll
    for (int ch = 0; ch < 2; ch++) {
        if (ch == 1) __syncthreads();
        const char* lbase = (const char*)lds4 + ch * 62208;
        const ushort* wbase = wT + (size_t)ch * 27 * 2048 + kgrp*8;
        short8 wq[3][2];
        #pragma unroll
        for (int pre = 0; pre < 3; pre++) {
            wq[pre][0] = *(const short8*)(wbase + (size_t)pre*2048 + coA*32);
            wq[pre][1] = *(const short8*)(wbase + (size_t)pre*2048 + coB*32);
        }
        __builtin_amdgcn_s_setprio(1);
        #pragma unroll
        for (int t = 0; t < 27; t++) {
            const int t0 = t / 9, t1 = (t / 3) % 3, t2 = t % 3;
            const int slot = t % 3;
            int x = l15 + t2;
            int inrow = (kgrp ^ ((x >> 1) & 3)) << 4;
            #pragma unroll
            for (int f = 0; f < 4; f++) {
                int y = ngroup*4 + f + t1;
                int vox = (t0*18 + y)*18 + x;
                short8 bfr = *(const short8*)(lbase + vox*64 + inrow);
                acc[0][f] = __builtin_amdgcn_mfma_f32_16x16x32_bf16(wq[slot][0], bfr, acc[0][f], 0, 0, 0);
                acc[1][f] = __builtin_amdgcn_mfma_f32_16x16x32_bf16(wq[slot][1], bfr, acc[1][f], 0, 0, 0);
            }
            if (t + 3 < 27) {
                wq[slot][0] = *(const short8*)(wbase + (size_t)(t+3)*2048 + coA*32);
                wq[slot][1] = *(const short8*)(wbase + (size_t)(t+3)*2048 + coB*32);
            }
        }
        __builtin_amdgcn_s_setprio(0);
    }
    int d2 = x0 + l15;
    #pragma unroll
    for (int f = 0; f < 4; f++) {
        int d1 = y0 + ngroup*4 + f;
        int vox = (d0*RR + d1)*RR + d2;
        ushort* dst = rawbf + ((size_t)b*R3 + vox)*64 + mgroup*32 + kgrp*4;
        ushort4v o0, o1;
        #pragma unroll
        for (int e = 0; e < 4; e++) { o0[e] = f2bf(acc[0][f][e]); o1[e] = f2bf(acc[1][f][e]); }
        *(ushort4v*)dst = o0;
        *(ushort4v*)(dst + 16) = o1;
    }
    // inline BN stats (exact, from f32 accumulators)
    __syncthreads();
    float* bins = (float*)lds4;
    if (tid < 128) bins[tid] = 0.f;
    __syncthreads();
    float sv[2][4], qv[2][4];
    #pragma unroll
    for (int mf = 0; mf < 2; mf++)
        #pragma unroll
        for (int e = 0; e < 4; e++) {
            float s = 0.f, q = 0.f;
            #pragma unroll
            for (int f = 0; f < 4; f++) {
                float v = acc[mf][f][e];
                s += v; q += v*v;
            }
            #pragma unroll
            for (int m = 1; m < 16; m <<= 1) {
                s += __shfl_xor(s, m);
                q += __shfl_xor(q, m);
            }
            sv[mf][e] = s; qv[mf][e] = q;
        }
    if (l15 == 0) {
        #pragma unroll
        for (int mf = 0; mf < 2; mf++)
            #pragma unroll
            for (int e = 0; e < 4; e++) {
                int co = mgroup*32 + mf*16 + kgrp*4 + e;
                atomicAdd(&bins[co], sv[mf][e]);
                atomicAdd(&bins[64 + co], qv[mf][e]);
            }
    }
    __syncthreads();
    if (tid < 64) { atomicAdd(&gs[tid], bins[tid]); atomicAdd(&gq[tid], bins[64 + tid]); }
}

// ------- point branch stats + store raw p as bf16 [b][64][N] (round-19) ------
__global__ __launch_bounds__(256) void k_point_stats_P(const ushort* __restrict__ featT,
                                                       const float* __restrict__ wp,
                                                       ushort* __restrict__ P,
                                                       float* __restrict__ gs,
                                                       float* __restrict__ gq) {
    __shared__ float ls[64], lq[64];
    int b = blockIdx.y;
    int n = blockIdx.x * 256 + threadIdx.x;
    if (threadIdx.x < 64) { ls[threadIdx.x] = 0.f; lq[threadIdx.x] = 0.f; }
    __syncthreads();
    f32x4 fr[16];
    const ushort8* fp = (const ushort8*)(featT + ((size_t)b*NPT + n)*64);
    #pragma unroll
    for (int r = 0; r < 8; r++) {
        ushort8 u = fp[r];
        #pragma unroll
        for (int e = 0; e < 8; e++)
            fr[(r*8 + e) >> 2][(r*8 + e) & 3] = bf2f(u[e]);
    }
    int lane = threadIdx.x & 63;
    #pragma unroll
    for (int co = 0; co < 64; co++) {
        float p = 0.f;
        #pragma unroll
        for (int r = 0; r < 16; r++) {
            f32x4 w4 = *(const f32x4*)(wp + co*64 + r*4);   // wave-uniform -> s_load
            p = fmaf(w4[0], fr[r][0], p); p = fmaf(w4[1], fr[r][1], p);
            p = fmaf(w4[2], fr[r][2], p); p = fmaf(w4[3], fr[r][3], p);
        }
        P[((size_t)(b*64 + co))*NPT + n] = f2bf(p);
        float s = p, q = p*p;
        #pragma unroll
        for (int m = 1; m < 64; m <<= 1) {
            s += __shfl_xor(s, m);
            q += __shfl_xor(q, m);
        }
        if (lane == 0) { atomicAdd(&ls[co], s); atomicAdd(&lq[co], q); }
    }
    __syncthreads();
    if (threadIdx.x < 64) {
        atomicAdd(&gs[threadIdx.x], ls[threadIdx.x]);
        atomicAdd(&gq[threadIdx.x], lq[threadIdx.x]);
    }
}

// ------ final: fused finalize(BN2,BNp) + devox(bn2+leaky) + point + add ------
__global__ __launch_bounds__(256) void k_final4(
    const ushort* __restrict__ x2raw, // [B][R3][64] conv2 RAW bf16 channel-last
    const float* __restrict__ norm,
    const ushort* __restrict__ P,     // [B][64][N] bf16 point-branch raw
    const float* __restrict__ gs2, const float* __restrict__ gq2,
    const float* __restrict__ g2, const float* __restrict__ be2,
    const float* __restrict__ gsp, const float* __restrict__ gqp,
    const float* __restrict__ gp, const float* __restrict__ bep,
    float* __restrict__ out)          // [B][64][N]
{
    __shared__ float s_sc[64], s_sh[64], s_scp[64], s_shp[64];
    int b = blockIdx.y;
    int tid = threadIdx.x;
    const float cntf = 262144.0f;
    if (tid < 64) {
        int c = tid;
        float m = gs2[c] / cntf;
        float vv = gq2[c] / cntf - m*m;
        float scv = g2[c] * rsqrtf(fmaxf(vv, 0.0f) + BN_EPS);
        s_sc[c] = scv; s_sh[c] = be2[c] - m*scv;
    } else if (tid < 128) {
        int c = tid - 64;
        float m = gsp[c] / cntf;
        float vv = gqp[c] / cntf - m*m;
        float scv = gp[c] * rsqrtf(fmaxf(vv, 0.0f) + BN_EPS);
        s_scp[c] = scv; s_shp[c] = bep[c] - m*scv;
    }
    __syncthreads();
    int pt = blockIdx.x * 64 + (tid & 63);
    int q = tid >> 6;                 // channel quarter, uniform per wave
    float v0 = norm[((size_t)b*3 + 0)*NPT + pt];
    float v1 = norm[((size_t)b*3 + 1)*NPT + pt];
    float v2 = norm[((size_t)b*3 + 2)*NPT + pt];
    int l0 = (int)floorf(v0), l1 = (int)floorf(v1), l2 = (int)floorf(v2);
    float f0 = v0 - (float)l0, f1 = v1 - (float)l1, f2 = v2 - (float)l2;
    int h0 = min(l0 + 1, RR - 1), h1 = min(l1 + 1, RR - 1), h2 = min(l2 + 1, RR - 1);

    f32x4 scv[4], shv[4];
    #pragma unroll
    for (int r = 0; r < 4; r++) {
        scv[r] = *(const f32x4*)&s_sc[q*16 + r*4];
        shv[r] = *(const f32x4*)&s_sh[q*16 + r*4];
    }

    f32x4 a4[4];
    #pragma unroll
    for (int r = 0; r < 4; r++) a4[r] = (f32x4)(0.0f);
    #pragma unroll
    for (int c = 0; c < 8; c++) {
        int xi = (c & 4) ? h0 : l0; float wx = (c & 4) ? f0 : 1.f - f0;
        int yi = (c & 2) ? h1 : l1; float wy = (c & 2) ? f1 : 1.f - f1;
        int zi = (c & 1) ? h2 : l2; float wz = (c & 1) ? f2 : 1.f - f2;
        float w = wx * wy * wz;
        const ushort* g = x2raw +
            ((size_t)b*R3 + (size_t)((xi*RR + yi)*RR + zi))*64 + q*16;
        ushort8 rv0 = *(const ushort8*)g;
        ushort8 rv1 = *(const ushort8*)(g + 8);
        #pragma unroll
        for (int r = 0; r < 2; r++) {
            #pragma unroll
            for (int e = 0; e < 4; e++) {
                float x = bf2f(rv0[r*4 + e])*scv[r][e] + shv[r][e];
                x = x >= 0.f ? x : 0.1f*x;
                a4[r][e] = fmaf(w, x, a4[r][e]);
                float x2 = bf2f(rv1[r*4 + e])*scv[2 + r][e] + shv[2 + r][e];
                x2 = x2 >= 0.f ? x2 : 0.1f*x2;
                a4[2 + r][e] = fmaf(w, x2, a4[2 + r][e]);
            }
        }
    }
    #pragma unroll
    for (int r = 0; r < 4; r++) {
        #pragma unroll
        for (int e = 0; e < 4; e++) {
            int co = q*16 + r*4 + e;
            float p = bf2f(P[((size_t)(b*64 + co))*NPT + pt]);
            p = p * s_scp[co] + s_shp[co];
            p = fmaxf(p, 0.f);
            out[((size_t)(b*64 + co))*NPT + pt] = a4[r][e] + p;
        }
    }
}

extern "C" void kernel_launch(void* const* d_in, const int* in_sizes, int n_in,
                              void* d_out, int out_size, void* d_ws, size_t ws_size,
                              hipStream_t stream) {
    const float* feat   = (const float*)d_in[0];
    const float* coords = (const float*)d_in[1];
    const float* w1  = (const float*)d_in[2];
    const float* g1  = (const float*)d_in[4];
    const float* be1 = (const float*)d_in[5];
    const float* w2  = (const float*)d_in[6];
    const float* g2  = (const float*)d_in[8];
    const float* be2 = (const float*)d_in[9];
    const float* wp  = (const float*)d_in[10];
    const float* gp  = (const float*)d_in[12];
    const float* bep = (const float*)d_in[13];
    float* out = (float*)d_out;
    float* ws  = (float*)d_ws;

    // workspace layout (float offsets):
    //   stats  384      -> [32, 416)            (s1,q1,s2,q2,sp,qp)
    //   norm   786432   -> [1024, 787456)
    //   nxt    262144   -> [787456, 1049600)    (int)
    //   head   314432   -> [1049600, 1364032)   (int, 8*RP3)
    //   rawbf  4194304  -> [1364032, 5558336)   bf16 [8][R3][64] conv raw out
    //   wT1    55296    -> [21487680, 21542976)
    //   wT2    55296    -> [21542976, 21598272)
    //   gbf    10061824 -> [21598272, 31660096)  bf16 padded grid
    //   P      8388608  -> [21598272, 29986880)  bf16; overlays gbf (dead after conv2)
    //   featT  8388608  -> [31660096, 40048704)  bf16 [8][N][64]
    float* mean   = ws;
    float* maxmag = ws + 24;
    float* stats  = ws + 32;
    float* norm   = ws + 1024;
    int*   nxt    = (int*)(ws + 787456);
    int*   head   = (int*)(ws + 1049600);
    ushort* rawbf = (ushort*)(ws + 1364032);
    ushort* wT1   = (ushort*)(ws + 21487680);
    ushort* wT2   = (ushort*)(ws + 21542976);
    ushort* gbf   = (ushort*)(ws + 21598272);
    ushort* P     = (ushort*)(ws + 21598272);
    ushort* featT = (ushort*)(ws + 31660096);

    hipMemsetAsync(stats, 0, 384 * sizeof(float), stream);
    hipMemsetAsync(head, 0xFF, 314432ull * sizeof(int), stream);   // head = -1

    k_wt2<<<864, 256, 0, stream>>>(w1, w2, wT1, wT2);
    k_mean  <<<24, 256, 0, stream>>>(coords, mean);
    k_maxmag<<<8, 256, 0, stream>>>(coords, mean, maxmag);
    k_norm  <<<dim3(128, 8), 256, 0, stream>>>(coords, mean, maxmag, norm, nxt, head);
    k_transpose<<<dim3(512, 8), 256, 0, stream>>>(feat, featT);
    k_gather<<<dim3(9826, 8), 256, 0, stream>>>(featT, head, nxt, gbf);

    // conv1 (+inline stats1): gbf -> rawbf (bf16)
    k_conv_mfma<<<dim3(32, 4, 8), 512, 0, stream>>>(gbf, wT1, rawbf, stats + 0, stats + 64);
    // fused finalize1 + BN1+leaky+pack: rawbf -> gbf
    k_bnpack<<<9826, 256, 0, stream>>>(rawbf, stats + 0, stats + 64, g1, be1, gbf);

    // conv2 (+inline stats2): gbf -> rawbf; gbf dead afterwards
    k_conv_mfma<<<dim3(32, 4, 8), 512, 0, stream>>>(gbf, wT2, rawbf, stats + 128, stats + 192);

    // point branch: compute p once, store bf16 into P (overlays dead gbf), stats
    k_point_stats_P<<<dim3(128, 8), 256, 0, stream>>>(featT, wp, P, stats + 256, stats + 320);

    // final: fused finalize(2,p) + devox BN2+leaky + point add
    k_final4<<<dim3(512, 8), 256, 0, stream>>>(rawbf, norm, P,
                                               stats + 128, stats + 192, g2, be2,
                                               stats + 256, stats + 320, gp, bep,
                                               out);
}